// Round 6
// baseline (385.094 us; speedup 1.0000x reference)
//
#include <hip/hip_runtime.h>
#include <hip/hip_bf16.h>

#define NN 100000   // nodes
#define FF 10       // input features
#define HH 20       // hidden dim
#define GG 512      // graphs
#define LL 2        // labels

#define NB 500      // dst buckets
#define BNODES 200  // nodes per bucket (NN / NB)
#define CAP 7168    // per-bucket edge capacity (mean 6400, sigma 80 -> 9.6σ)
#define TILE 4096   // edges per block in multisplit
#define SRC_BITS 17
#define SRC_MASK 0x1FFFFu

typedef float vfloat4 __attribute__((ext_vector_type(4)));
typedef float vfloat2 __attribute__((ext_vector_type(2)));

// bf16 helpers (storage-only; all math in f32)
__device__ inline unsigned short f2bf(float f) {
  unsigned u = __float_as_uint(f);
  unsigned r = u + 0x7FFFu + ((u >> 16) & 1u);
  return (unsigned short)(r >> 16);
}
__device__ inline float bflo(unsigned u) { return __uint_as_float(u << 16); }
__device__ inline float bfhi(unsigned u) { return __uint_as_float(u & 0xFFFF0000u); }

// ---------------------------------------------------------------------------
// Cast x f32->bf16 and zero accumulators / cursors (folded memsets).
// ---------------------------------------------------------------------------
__global__ __launch_bounds__(256) void cast_init_kernel(
    const float* __restrict__ x, unsigned short* __restrict__ xb,
    float* __restrict__ sump, int* __restrict__ maxp, float* __restrict__ cnt,
    int* __restrict__ cursor, int n) {
  int i = blockIdx.x * 256 + threadIdx.x;
  if (i < n) xb[i] = f2bf(x[i]);
  if (i < GG * HH) {
    sump[i] = 0.0f;
    maxp[i] = 0;
  }
  if (i < GG) cnt[i] = 0.0f;
  if (i < NB) cursor[i] = 0;
}

// ---------------------------------------------------------------------------
// K1: slim multisplit into FIXED per-bucket regions [bk*CAP, ...).
// Pass 1: LDS histogram of this tile (dst read #1).
// Reserve: one global atomic per (block, non-empty bucket).
// Pass 2: re-read tile (L2-hot) and write payloads into block-owned runs.
// Payload pack: (local_dst << 17) | src.
// ---------------------------------------------------------------------------
__global__ __launch_bounds__(256) void multisplit_kernel(
    const int* __restrict__ src, const int* __restrict__ dst,
    int* __restrict__ cursor, unsigned int* __restrict__ pay, int E) {
  __shared__ int lhist[NB];
  __shared__ int gbase[NB];
  __shared__ int lcur[NB];
  int t = threadIdx.x;
  for (int i = t; i < NB; i += 256) lhist[i] = 0;
  __syncthreads();

  int base = blockIdx.x * TILE;
  for (int i = t; i < TILE; i += 256) {
    int e = base + i;
    if (e < E) atomicAdd(&lhist[__builtin_nontemporal_load(dst + e) / BNODES], 1);
  }
  __syncthreads();

  for (int i = t; i < NB; i += 256) {
    int c = lhist[i];
    gbase[i] = (c ? atomicAdd(&cursor[i], c) : 0) + i * CAP;
    lcur[i] = 0;
  }
  __syncthreads();

  for (int i = t; i < TILE; i += 256) {
    int e = base + i;
    if (e < E) {
      int d = dst[e];
      int s = __builtin_nontemporal_load(src + e);
      int bk = d / BNODES;
      int ld = d - bk * BNODES;
      int r = atomicAdd(&lcur[bk], 1);
      pay[gbase[bk] + r] = ((unsigned)ld << SRC_BITS) | (unsigned)s;
    }
  }
}

// ---------------------------------------------------------------------------
// K2: per-bucket CSR finalize. One block owns a 200-node bucket; scattered
// writes confined to the block-owned [b*CAP, b*CAP+count) range.
// rofs/rend are absolute indices into the padded srt array.
// ---------------------------------------------------------------------------
__global__ __launch_bounds__(256) void bucket_csr_kernel(
    const unsigned int* __restrict__ pay, const int* __restrict__ cursor,
    int* __restrict__ srt, int* __restrict__ rofs, int* __restrict__ rend) {
  __shared__ int lhist[BNODES];
  __shared__ int lofs[BNODES];
  __shared__ int lcur[BNODES];
  __shared__ int ss[256];
  int b = blockIdx.x;
  int t = threadIdx.x;
  int k0 = b * CAP;
  int k1 = k0 + cursor[b];

  if (t < BNODES) lhist[t] = 0;
  __syncthreads();
  for (int k = k0 + t; k < k1; k += 256)
    atomicAdd(&lhist[__builtin_nontemporal_load(pay + k) >> SRC_BITS], 1);
  __syncthreads();

  int own = (t < BNODES) ? lhist[t] : 0;
  ss[t] = own;
  __syncthreads();
  for (int off = 1; off < 256; off <<= 1) {
    int a0 = (t >= off) ? ss[t - off] : 0;
    __syncthreads();
    ss[t] += a0;
    __syncthreads();
  }
  if (t < BNODES) {
    int ex = ss[t] - own;
    lofs[t] = ex;
    lcur[t] = 0;
    rofs[b * BNODES + t] = k0 + ex;
    rend[b * BNODES + t] = k0 + ex + own;
  }
  __syncthreads();

  for (int k = k0 + t; k < k1; k += 256) {
    unsigned int p = pay[k];
    int ld = p >> SRC_BITS;
    int s = (int)(p & SRC_MASK);
    int r = atomicAdd(&lcur[ld], 1);
    srt[k0 + lofs[ld] + r] = s;
  }
}

// ---------------------------------------------------------------------------
// Gather (bf16 rows): thread per (node, chunk); 5 chunks cover a row.
// DIN=20: chunk = 4 bf16 (8B uint2). DIN=10: chunk = 2 bf16 (4B uint).
// f32 accumulation, 4x edge unroll. srt via nt loads (stream), agg nt store.
// ---------------------------------------------------------------------------
template<int DIN>
__global__ __launch_bounds__(256) void gather_bf16_kernel(
    const unsigned short* __restrict__ xin, const int* __restrict__ rofs,
    const int* __restrict__ rend, const int* __restrict__ srt,
    float* __restrict__ agg, int n_nodes) {
  int id = blockIdx.x * 256 + threadIdx.x;
  if (id >= n_nodes * 5) return;
  int n = id / 5;
  int c = id - n * 5;
  int k0 = rofs[n], k1 = rend[n];
  float a0 = 0, a1 = 0, a2 = 0, a3 = 0;
  if (DIN == 20) {
    const unsigned short* xb = xin + c * 4;
    int k = k0;
    for (; k + 3 < k1; k += 4) {
      int s0 = __builtin_nontemporal_load(srt + k);
      int s1 = __builtin_nontemporal_load(srt + k + 1);
      int s2 = __builtin_nontemporal_load(srt + k + 2);
      int s3 = __builtin_nontemporal_load(srt + k + 3);
      uint2 u0 = *(const uint2*)(xb + (size_t)s0 * 20);
      uint2 u1 = *(const uint2*)(xb + (size_t)s1 * 20);
      uint2 u2 = *(const uint2*)(xb + (size_t)s2 * 20);
      uint2 u3 = *(const uint2*)(xb + (size_t)s3 * 20);
      a0 += bflo(u0.x) + bflo(u1.x) + bflo(u2.x) + bflo(u3.x);
      a1 += bfhi(u0.x) + bfhi(u1.x) + bfhi(u2.x) + bfhi(u3.x);
      a2 += bflo(u0.y) + bflo(u1.y) + bflo(u2.y) + bflo(u3.y);
      a3 += bfhi(u0.y) + bfhi(u1.y) + bfhi(u2.y) + bfhi(u3.y);
    }
    for (; k < k1; k++) {
      int s = __builtin_nontemporal_load(srt + k);
      uint2 u = *(const uint2*)(xb + (size_t)s * 20);
      a0 += bflo(u.x);
      a1 += bfhi(u.x);
      a2 += bflo(u.y);
      a3 += bfhi(u.y);
    }
    vfloat4 v = {a0, a1, a2, a3};
    __builtin_nontemporal_store(v, (vfloat4*)(agg + (size_t)n * 20 + c * 4));
  } else {
    const unsigned short* xb = xin + c * 2;
    int k = k0;
    for (; k + 3 < k1; k += 4) {
      int s0 = __builtin_nontemporal_load(srt + k);
      int s1 = __builtin_nontemporal_load(srt + k + 1);
      int s2 = __builtin_nontemporal_load(srt + k + 2);
      int s3 = __builtin_nontemporal_load(srt + k + 3);
      unsigned u0 = *(const unsigned*)(xb + (size_t)s0 * 10);
      unsigned u1 = *(const unsigned*)(xb + (size_t)s1 * 10);
      unsigned u2 = *(const unsigned*)(xb + (size_t)s2 * 10);
      unsigned u3 = *(const unsigned*)(xb + (size_t)s3 * 10);
      a0 += bflo(u0) + bflo(u1) + bflo(u2) + bflo(u3);
      a1 += bfhi(u0) + bfhi(u1) + bfhi(u2) + bfhi(u3);
    }
    for (; k < k1; k++) {
      int s = __builtin_nontemporal_load(srt + k);
      unsigned u = *(const unsigned*)(xb + (size_t)s * 10);
      a0 += bflo(u);
      a1 += bfhi(u);
    }
    vfloat2 v = {a0, a1};
    __builtin_nontemporal_store(v, (vfloat2*)(agg + (size_t)n * 10 + c * 2));
  }
}

// ---------------------------------------------------------------------------
// Dense (layers 1,2): thread per (node, out-feature), weights in LDS.
// agg f32 (nt loads, streamed), root input bf16, output bf16.
// ---------------------------------------------------------------------------
template<int DIN>
__global__ __launch_bounds__(256) void dense_relu_kernel(
    const float* __restrict__ agg, const unsigned short* __restrict__ xin,
    const float* __restrict__ Wrel, const float* __restrict__ b,
    const float* __restrict__ Wroot, unsigned short* __restrict__ out,
    int n_nodes) {
  __shared__ float sWrel[DIN * HH];
  __shared__ float sWroot[DIN * HH];
  __shared__ float sb[HH];
  for (int i = threadIdx.x; i < DIN * HH; i += 256) {
    sWrel[i] = Wrel[i];
    sWroot[i] = Wroot[i];
  }
  if (threadIdx.x < HH) sb[threadIdx.x] = b[threadIdx.x];
  __syncthreads();
  int idx = blockIdx.x * 256 + threadIdx.x;
  if (idx >= n_nodes * HH) return;
  int n = idx / HH;
  int j = idx - n * HH;
  const float* ar = agg + (size_t)n * DIN;
  const unsigned short* xr = xin + (size_t)n * DIN;
  float acc = sb[j];
#pragma unroll
  for (int f = 0; f < DIN; f++) {
    acc += ar[f] * sWrel[f * HH + j];
    acc += bflo((unsigned)xr[f]) * sWroot[f * HH + j];
  }
  out[idx] = f2bf(fmaxf(acc, 0.0f));
}

// ---------------------------------------------------------------------------
// Layer-3 dense + pool. Thread per node computes o[20]; pooling via
// wave-segmented shuffle reduction (batch sorted -> ~1.3 segments/wave),
// then ~40 global atomics per segment from the lead lane. No LDS atomics.
// Post-ReLU >= 0 -> int atomicMax on float bits order-correct; zero init
// reproduces where(cnt>0, max, 0).
// ---------------------------------------------------------------------------
__global__ __launch_bounds__(256) void dense_pool_kernel(
    const float* __restrict__ agg, const unsigned short* __restrict__ xin,
    const float* __restrict__ Wrel, const float* __restrict__ bb,
    const float* __restrict__ Wroot, const int* __restrict__ batch,
    float* __restrict__ sump, int* __restrict__ maxp, float* __restrict__ cnt,
    int n_nodes) {
  __shared__ float sWrel[HH * HH];
  __shared__ float sWroot[HH * HH];
  __shared__ float sb[HH];
  int t = threadIdx.x;
  for (int i = t; i < HH * HH; i += 256) {
    sWrel[i] = Wrel[i];
    sWroot[i] = Wroot[i];
  }
  if (t < HH) sb[t] = bb[t];
  __syncthreads();

  int n = blockIdx.x * 256 + t;
  bool valid = (n < n_nodes);
  float o[HH];
#pragma unroll
  for (int j = 0; j < HH; j++) o[j] = 0.0f;
  int g = -1;

  if (valid) {
    float ar[HH], xr[HH];
    const float* ap = agg + (size_t)n * HH;
    const uint2* xp = (const uint2*)(xin + (size_t)n * HH);
#pragma unroll
    for (int c = 0; c < 5; c++) {
      float4 v = *(const float4*)(ap + 4 * c);
      ar[4 * c + 0] = v.x; ar[4 * c + 1] = v.y;
      ar[4 * c + 2] = v.z; ar[4 * c + 3] = v.w;
      uint2 u = xp[c];
      xr[4 * c + 0] = bflo(u.x); xr[4 * c + 1] = bfhi(u.x);
      xr[4 * c + 2] = bflo(u.y); xr[4 * c + 3] = bfhi(u.y);
    }
#pragma unroll
    for (int j = 0; j < HH; j++) o[j] = sb[j];
#pragma unroll
    for (int f = 0; f < HH; f++) {
      float a = ar[f], xv = xr[f];
#pragma unroll
      for (int j = 0; j < HH; j++)
        o[j] += a * sWrel[f * HH + j] + xv * sWroot[f * HH + j];
    }
#pragma unroll
    for (int j = 0; j < HH; j++) o[j] = fmaxf(o[j], 0.0f);
    g = batch[n];
  }

  int lane = t & 63;
  unsigned long long remaining = __ballot(valid);
  while (remaining) {
    int lead = __ffsll(remaining) - 1;
    int gcur = __shfl(g, lead);
    bool mine = valid && (g == gcur);
    unsigned long long seg = __ballot(mine);
    float s[HH], m[HH];
#pragma unroll
    for (int j = 0; j < HH; j++) {
      s[j] = mine ? o[j] : 0.0f;
      m[j] = mine ? o[j] : 0.0f;
    }
#pragma unroll
    for (int off = 32; off >= 1; off >>= 1) {
#pragma unroll
      for (int j = 0; j < HH; j++) {
        s[j] += __shfl_xor(s[j], off);
        m[j] = fmaxf(m[j], __shfl_xor(m[j], off));
      }
    }
    if (lane == lead) {
#pragma unroll
      for (int j = 0; j < HH; j++) {
        atomicAdd(&sump[gcur * HH + j], s[j]);
        atomicMax(&maxp[gcur * HH + j], __float_as_int(m[j]));
      }
      atomicAdd(&cnt[gcur], (float)__popcll(seg));
    }
    remaining &= ~seg;
  }
}

__global__ __launch_bounds__(256) void readout_kernel(
    const float* __restrict__ sump, const int* __restrict__ maxp,
    const float* __restrict__ cnt, const float* __restrict__ Wlin,
    const float* __restrict__ blin, float* __restrict__ out) {
  int idx = blockIdx.x * 256 + threadIdx.x;
  if (idx >= GG * LL) return;
  int g = idx / LL;
  int l = idx - g * LL;
  float c = cnt[g];
  float inv = 1.0f / fmaxf(c, 1.0f);
  float acc = blin[l];
#pragma unroll
  for (int j = 0; j < HH; j++) {
    float mx = __int_as_float(maxp[g * HH + j]);
    float mean = sump[g * HH + j] * inv;
    acc += mx * Wlin[j * LL + l];
    acc += mean * Wlin[(HH + j) * LL + l];
  }
  out[idx] = acc;
}

extern "C" void kernel_launch(void* const* d_in, const int* in_sizes, int n_in,
                              void* d_out, int out_size, void* d_ws,
                              size_t ws_size, hipStream_t stream) {
  const float* x = (const float*)d_in[0];
  const int* edge_index = (const int*)d_in[1];
  const int* batch = (const int*)d_in[2];
  const float* W_rel1 = (const float*)d_in[3];
  const float* b1 = (const float*)d_in[4];
  const float* W_root1 = (const float*)d_in[5];
  const float* W_rel2 = (const float*)d_in[6];
  const float* b2 = (const float*)d_in[7];
  const float* W_root2 = (const float*)d_in[8];
  const float* W_rel3 = (const float*)d_in[9];
  const float* b3 = (const float*)d_in[10];
  const float* W_root3 = (const float*)d_in[11];
  const float* W_lin = (const float*)d_in[12];
  const float* b_lin = (const float*)d_in[13];
  float* out = (float*)d_out;

  const int E = in_sizes[1] / 2;
  const int n_nodes = in_sizes[0] / FF;  // == NN
  const int* src = edge_index;
  const int* dst = edge_index + E;

  // Workspace layout. pay is dead after bucket_csr; agg (8MB) aliases it
  // (NB*CAP*4 = 14.3MB). All chunks multiples of 4 ints -> 16B aligned.
  unsigned int* pay = (unsigned int*)d_ws;       // NB*CAP u32 | aliased: agg
  int* srt = (int*)(pay + (size_t)NB * CAP);     // NB*CAP
  int* rofs = srt + (size_t)NB * CAP;            // NN
  int* rend = rofs + NN;                         // NN
  int* cursor = rend + NN;                       // 512
  float* sump = (float*)(cursor + 512);          // GG*HH
  int* maxp = (int*)(sump + GG * HH);            // GG*HH
  float* cnt = (float*)(maxp + GG * HH);         // 512
  unsigned short* xb = (unsigned short*)(cnt + 512);  // NN*FF bf16 (2MB)
  unsigned short* h1 = xb + (size_t)NN * FF;     // NN*HH bf16 (4MB)
  unsigned short* h2 = h1 + (size_t)NN * HH;     // NN*HH bf16 (4MB)
  float* agg = (float*)pay;                      // NN*HH f32 (after CSR)

  const int edge_tiles = (E + TILE - 1) / TILE;
  const int gath_blocks = (n_nodes * 5 + 255) / 256;
  const int node_blocks = (n_nodes + 255) / 256;
  const int nodeF_blocks = (n_nodes * HH + 255) / 256;

  // ---- Cast x to bf16 + zero accumulators/cursors ----
  cast_init_kernel<<<(n_nodes * FF + 255) / 256, 256, 0, stream>>>(
      x, xb, sump, maxp, cnt, cursor, n_nodes * FF);

  // ---- CSR build: slim multisplit into fixed bucket regions + finalize ----
  multisplit_kernel<<<edge_tiles, 256, 0, stream>>>(src, dst, cursor, pay, E);
  bucket_csr_kernel<<<NB, 256, 0, stream>>>(pay, cursor, srt, rofs, rend);

  // ---- Layer 1: F(10) -> H(20) ----
  gather_bf16_kernel<FF><<<gath_blocks, 256, 0, stream>>>(
      xb, rofs, rend, srt, agg, n_nodes);
  dense_relu_kernel<FF><<<nodeF_blocks, 256, 0, stream>>>(
      agg, xb, W_rel1, b1, W_root1, h1, n_nodes);

  // ---- Layer 2: H -> H ----
  gather_bf16_kernel<HH><<<gath_blocks, 256, 0, stream>>>(
      h1, rofs, rend, srt, agg, n_nodes);
  dense_relu_kernel<HH><<<nodeF_blocks, 256, 0, stream>>>(
      agg, h1, W_rel2, b2, W_root2, h2, n_nodes);

  // ---- Layer 3: H -> H, dense + wave-segmented pool ----
  gather_bf16_kernel<HH><<<gath_blocks, 256, 0, stream>>>(
      h2, rofs, rend, srt, agg, n_nodes);
  dense_pool_kernel<<<node_blocks, 256, 0, stream>>>(
      agg, h2, W_rel3, b3, W_root3, batch, sump, maxp, cnt, n_nodes);

  // ---- Readout ----
  readout_kernel<<<(GG * LL + 255) / 256, 256, 0, stream>>>(
      sump, maxp, cnt, W_lin, b_lin, out);
}